// Round 2
// baseline (133.251 us; speedup 1.0000x reference)
//
#include <hip/hip_runtime.h>

#define N_ROWS 16384
#define K_CB   8192
#define D_DIM  64
#define NSPLIT 16
#define SPLIT_K (K_CB / NSPLIT)          // 512
#define STAGE  64                        // codebook rows per LDS stage (two 32-n tiles)
#define NSTAGES (SPLIT_K / STAGE)        // 8  -> slot = 2*s+u in [0,16): 4 bits
#define BLKT   256                       // 4 waves, 2 m-tiles/wave -> 256 rows/block

typedef unsigned short u16;
typedef unsigned int   u32;
typedef unsigned long long u64;
typedef __attribute__((ext_vector_type(8)))  short short8v;  // 8 bf16 (4 VGPRs)
typedef __attribute__((ext_vector_type(16))) float f32x16;   // 32x32 MFMA C/D

static __device__ __forceinline__ u16 f2bf(float f) {        // RNE fp32->bf16
    unsigned u = __float_as_uint(f);
    return (u16)((u + 0x7FFFu + ((u >> 16) & 1u)) >> 16);
}

// ---- kernel 0: codebook prep. bf16 cast + 0.5*||c||^2. 8 rows/block. ----
// Single-product bf16 scoring: no lo-half needed. Residual error (~0.02 std)
// is absorbed by the exact fp32 top-2 rescore (top-score spacing ~2.4 for
// 8192 gaussian codewords: ~100 sigma margin).
__global__ void vq_prep_kernel(const float* __restrict__ cb,
                               u16* __restrict__ cb_hi, float* __restrict__ hcsq)
{
    const int wave = threadIdx.x >> 6;
    const int lane = threadIdx.x & 63;
#pragma unroll
    for (int rr = 0; rr < 2; ++rr) {
        const int r = blockIdx.x * 8 + wave * 2 + rr;
        const float v = cb[r * D_DIM + lane];
        cb_hi[r * D_DIM + lane] = f2bf(v);
        float d = v * v;
#pragma unroll
        for (int m = 1; m < 64; m <<= 1) d += __shfl_xor(d, m, 64);
        if (lane == 0) hcsq[r] = 0.5f * d;
    }
}

// ---- kernel 1: 32x32x16 MFMA scores, 2 m-tiles/wave (64 rows), 4 waves,
//      single bf16 product, float-key argmax + exact fp32 top-2 rescore ----
// score(m,n) = dot(x_m, c_n) - 0.5||c_n||^2 ; argmin dist == argmax score.
// A operand: m=lane&31, k=(lane>>5)*8+j. B operand: n=lane&31, k=(lane>>5)*8+j.
// C/D: col(n)=lane&31, row(m)=(reg&3)+8*(reg>>2)+4*(lane>>5)   [m74/m101].
// Key: bits(score) & ~15 | slot, kept with v_max_f32 (<=15 ulp perturbation,
// absorbed by exact top-2 rescore); slot = 2*stage+subtile recovers cidx.
//
// R2 rationale: R1 counters showed MFMA/VALU/LDS pipes each at ~49k cyc/CU,
// nearly serialized (sum ~= runtime). Dropping the hi/lo compensation cuts
// MFMA 3x; 2 m-tiles/wave amortizes each B-fragment over 8 MFMAs (LDS 4x
// down); DMA bytes halve. VALU (key update) becomes the dominant pipe.
__global__ __launch_bounds__(BLKT, 4) void vq_mfma_kernel(
    const float* __restrict__ enc, const float* __restrict__ cb,
    const u16* __restrict__ cb_hi, const float* __restrict__ hcsq,
    u64* __restrict__ winner)
{
    // loop phase: ldsb 2 bufs x 8KB (4096 u32) | lds_h 2KB  = 18.25 KB
    // epilogue:   keys[256][33] (8448 u32) reuses everything (ldsb/lds_h dead)
    // block LDS = 33792 B -> 4 blocks/CU.
    __shared__ __align__(16) u32 smem[8448];
    u16*   ldsb  = (u16*)smem;                 // [0, 4096) u32
    float* lds_h = (float*)(smem + 4096);      // [4096, 4608) u32
    u32*   keys  = smem;                       // epilogue reuse

    const int tid  = threadIdx.x;
    const int w    = tid >> 6;                             // 0..3
    const int lane = tid & 63;
    const int n32  = lane & 31;
    const int lh   = lane >> 5;
    const int B0   = blockIdx.y * SPLIT_K;
    const int rowbase = blockIdx.x * 256 + w * 64;         // 64 m-rows per wave

    // ---- A fragments: 2 m-tiles x 4 k-chunks, converted once ----
    short8v a_hi[2][4];
#pragma unroll
    for (int mt = 0; mt < 2; ++mt) {
        const float* arow = enc + (size_t)(rowbase + mt * 32 + n32) * D_DIM + lh * 8;
#pragma unroll
        for (int c = 0; c < 4; ++c) {
            const float4 u0 = ((const float4*)(arow + c * 16))[0];
            const float4 u1 = ((const float4*)(arow + c * 16))[1];
            const float vv[8] = {u0.x,u0.y,u0.z,u0.w,u1.x,u1.y,u1.z,u1.w};
            short8v h8;
#pragma unroll
            for (int j = 0; j < 8; ++j) h8[j] = (short)f2bf(vv[j]);
            a_hi[mt][c] = h8;
        }
    }

    // ---- split's hcsq into LDS (once) ----
#pragma unroll
    for (int i = 0; i < SPLIT_K / BLKT; ++i)               // 2 iters
        lds_h[tid + i * BLKT] = hcsq[B0 + tid + i * BLKT];

    // ---- DMA: 8 granules/stage = 4 waves x 2; wave owns (u, cpair) ----
    // granule slot = lane (n=lane&31, octet=2c+lh) -> contiguous b128 dest.
    const int uu  = w & 1;                                 // 32-n subtile
    const int cb0 = w >> 1;                                // c parity
    const u16* gbase = cb_hi + (size_t)B0 * D_DIM;

#define DMA_STAGE(buf_, s_)                                                      \
    do {                                                                         \
        _Pragma("unroll")                                                        \
        for (int i_ = 0; i_ < 2; ++i_) {                                         \
            const int c_ = cb0 + 2 * i_;                                         \
            __builtin_amdgcn_global_load_lds(                                    \
                (const __attribute__((address_space(1))) void*)                  \
                    (gbase + ((size_t)(s_) * STAGE + uu * 32 + n32) * D_DIM      \
                           + (2 * c_ + lh) * 8),                                 \
                (__attribute__((address_space(3))) void*)                        \
                    (ldsb + (buf_) * 4096 + uu * 2048 + c_ * 512),               \
                16, 0, 0);                                                       \
        }                                                                        \
    } while (0)

    DMA_STAGE(0, 0);
    __syncthreads();                                       // stage 0 resident

    f32x16 z;
#pragma unroll
    for (int r = 0; r < 16; ++r) z[r] = 0.f;               // never written: chain seed

    float bkey[2][16];
#pragma unroll
    for (int mt = 0; mt < 2; ++mt)
#pragma unroll
        for (int r = 0; r < 16; ++r) bkey[mt][r] = -INFINITY;

    for (int s = 0; s < NSTAGES; ++s) {
        const int buf = s & 1;
        DMA_STAGE(buf ^ 1, (s + 1) & (NSTAGES - 1));       // async prefetch (wrap ok)

#pragma unroll
        for (int u = 0; u < 2; ++u) {                      // two 32-n subtiles
            const u16* bb = ldsb + buf * 4096 + u * 2048;
            short8v bh[4];
#pragma unroll
            for (int c = 0; c < 4; ++c)
                bh[c] = *(const short8v*)(bb + c * 512 + lane * 8);
            const float h = lds_h[s * STAGE + u * 32 + n32];
            const u32 slot = (u32)(s * 2 + u);             // 4 bits

#pragma unroll
            for (int mt = 0; mt < 2; ++mt) {               // independent 4-chains
                f32x16 acc;
                acc = __builtin_amdgcn_mfma_f32_32x32x16_bf16(a_hi[mt][0], bh[0], z,   0,0,0);
                acc = __builtin_amdgcn_mfma_f32_32x32x16_bf16(a_hi[mt][1], bh[1], acc, 0,0,0);
                acc = __builtin_amdgcn_mfma_f32_32x32x16_bf16(a_hi[mt][2], bh[2], acc, 0,0,0);
                acc = __builtin_amdgcn_mfma_f32_32x32x16_bf16(a_hi[mt][3], bh[3], acc, 0,0,0);

                // vector sub: broadcast -h, lets compiler pack v_pk_add_f32
                const f32x16 scv = acc - h;
#pragma unroll
                for (int r = 0; r < 16; ++r) {
                    const u32 kb = (__float_as_uint(scv[r]) & 0xFFFFFFF0u) | slot;
                    bkey[mt][r] = fmaxf(bkey[mt][r], __uint_as_float(kb));
                }
            }
        }
        __syncthreads();   // all waves done reading buf; prefetch drained (vmcnt0)
    }
#undef DMA_STAGE

    // ---- per-class winners -> keys[row][cls] in LDS (reuses ldsb region) ----
#pragma unroll
    for (int mt = 0; mt < 2; ++mt)
#pragma unroll
        for (int r = 0; r < 16; ++r) {
            const int m = (r & 3) + 8 * (r >> 2) + 4 * lh;
            keys[(w * 64 + mt * 32 + m) * 33 + n32] = __float_as_uint(bkey[mt][r]);
        }
    __syncthreads();

    // ---- top-2 of 32 classes (1 thread per row), exact fp32 rescore both ----
    {
        float k1 = -INFINITY, k2 = -INFINITY; int c1i = 0, c2i = 0;
#pragma unroll
        for (int cls = 0; cls < 32; ++cls) {
            const float kf = __uint_as_float(keys[tid * 33 + cls]);
            if (kf > k1)      { k2 = k1; c2i = c1i; k1 = kf; c1i = cls; }
            else if (kf > k2) { k2 = kf; c2i = cls; }
        }
        const int idx1 = B0 + (int)(__float_as_uint(k1) & 15u) * 32 + c1i;
        const int idx2 = B0 + (int)(__float_as_uint(k2) & 15u) * 32 + c2i;
        const int grow = blockIdx.x * 256 + tid;

        const float4* xp  = (const float4*)(enc + (size_t)grow * D_DIM);
        const float4* cp1 = (const float4*)(cb  + (size_t)idx1 * D_DIM);
        const float4* cp2 = (const float4*)(cb  + (size_t)idx2 * D_DIM);
        float d1 = 0.f, d2 = 0.f;
#pragma unroll
        for (int i = 0; i < 16; ++i) {
            const float4 xv = xp[i], v1 = cp1[i], v2 = cp2[i];
            float t;
            t = xv.x - v1.x; d1 = fmaf(t, t, d1);
            t = xv.y - v1.y; d1 = fmaf(t, t, d1);
            t = xv.z - v1.z; d1 = fmaf(t, t, d1);
            t = xv.w - v1.w; d1 = fmaf(t, t, d1);
            t = xv.x - v2.x; d2 = fmaf(t, t, d2);
            t = xv.y - v2.y; d2 = fmaf(t, t, d2);
            t = xv.z - v2.z; d2 = fmaf(t, t, d2);
            t = xv.w - v2.w; d2 = fmaf(t, t, d2);
        }
        // (distbits, idx) packed: u64 min == (min dist, then min idx) = jnp first-min.
        // 0xAAAA... ws poison exceeds any packed value (dist sign bit 0): free sentinel.
        atomicMin(winner + grow, ((u64)__float_as_uint(d1) << 32) | (u32)idx1);
        atomicMin(winner + grow, ((u64)__float_as_uint(d2) << 32) | (u32)idx2);
    }
}

// ---- kernel 2: gather winning codeword rows ----
__global__ void vq_gather_kernel(const float* __restrict__ cb,
                                 const u64* __restrict__ winner,
                                 float* __restrict__ out)
{
    const int g   = blockIdx.x * 256 + threadIdx.x;    // 262144 threads x 16B
    const int row = g >> 4;
    const int c4  = g & 15;
    const int idx = (int)(winner[row] & 0xFFFFFFFFu);
    ((float4*)(out + (size_t)row * D_DIM))[c4] =
        ((const float4*)(cb + (size_t)idx * D_DIM))[c4];
}

extern "C" void kernel_launch(void* const* d_in, const int* in_sizes, int n_in,
                              void* d_out, int out_size, void* d_ws, size_t ws_size,
                              hipStream_t stream) {
    const float* enc = (const float*)d_in[0];   // 16384 x 64 fp32
    const float* cb  = (const float*)d_in[1];   // 8192 x 64 fp32
    float* out = (float*)d_out;

    // ws layout (~1.16 MB): cb_hi | hcsq | winner
    u16* cb_hi  = (u16*)d_ws;                       // 1 MB
    float* hcsq = (float*)(cb_hi + K_CB * D_DIM);   // 32 KB
    u64* winner = (u64*)(hcsq + K_CB);              // 128 KB (8-byte aligned)

    vq_prep_kernel<<<K_CB / 8, 256, 0, stream>>>(cb, cb_hi, hcsq);

    dim3 g1(N_ROWS / 256, NSPLIT);                  // 64 x 16 = 1024 blocks of 256 thr
    vq_mfma_kernel<<<g1, BLKT, 0, stream>>>(enc, cb, cb_hi, hcsq, winner);

    vq_gather_kernel<<<(N_ROWS * 16) / 256, 256, 0, stream>>>(cb, winner, out);
}

// Round 3
// 102.105 us; speedup vs baseline: 1.3050x; 1.3050x over previous
//
#include <hip/hip_runtime.h>

#define N_ROWS 16384
#define K_CB   8192
#define D_DIM  64
#define NSPLIT 8
#define SPLIT_K (K_CB / NSPLIT)          // 1024
#define STAGE  64                        // codebook rows per LDS stage (two 32-n tiles)
#define NSTAGES (SPLIT_K / STAGE)        // 16  -> slot = 2*s+u in [0,32): 5 bits
#define BLKT   256                       // 4 waves per block, 1 m-tile (32 rows) per wave

typedef unsigned short u16;
typedef unsigned int   u32;
typedef unsigned long long u64;
typedef __attribute__((ext_vector_type(8)))  short short8v;  // 8 bf16 (4 VGPRs)
typedef __attribute__((ext_vector_type(16))) float f32x16;   // 32x32 MFMA C/D

static __device__ __forceinline__ u16 f2bf(float f) {        // RNE fp32->bf16
    unsigned u = __float_as_uint(f);
    return (u16)((u + 0x7FFFu + ((u >> 16) & 1u)) >> 16);
}

// ---- kernel 0: codebook prep. bf16 cast + 0.5*||c||^2. 8 rows/block. ----
// Single-product bf16 scoring: residual error (~0.02 std) is absorbed by the
// exact fp32 top-2 rescore (top-score spacing ~2.4 for 8192 gaussian
// codewords: huge margin). R2 post-mortem confirmed the MFMA-work arithmetic.
__global__ void vq_prep_kernel(const float* __restrict__ cb,
                               u16* __restrict__ cb_hi, float* __restrict__ hcsq)
{
    const int wave = threadIdx.x >> 6;
    const int lane = threadIdx.x & 63;
#pragma unroll
    for (int rr = 0; rr < 2; ++rr) {
        const int r = blockIdx.x * 8 + wave * 2 + rr;
        const float v = cb[r * D_DIM + lane];
        cb_hi[r * D_DIM + lane] = f2bf(v);
        float d = v * v;
#pragma unroll
        for (int m = 1; m < 64; m <<= 1) d += __shfl_xor(d, m, 64);
        if (lane == 0) hcsq[r] = 0.5f * d;
    }
}

// ---- kernel 1: 32x32x16 MFMA scores, 1 m-tile/wave (32 rows), 4 waves,
//      single bf16 product, float-key argmax + exact fp32 top-2 rescore ----
// R3 = R1 skeleton (proven: no spills, WRITE 4MB, 67us) minus the lo-product.
// ONE change only; R2 regressed by bundling 5 changes (spill disaster:
// persistent regs 64 -> WRITE_SIZE 61MB of scratch).
// score(m,n) = dot(x_m, c_n) - 0.5||c_n||^2 ; argmin dist == argmax score.
// A operand: m=lane&31, k=(lane>>5)*8+j. B operand: n=lane&31, k=(lane>>5)*8+j.
// C/D: col(n)=lane&31, row(m)=(reg&3)+8*(reg>>2)+4*(lane>>5)   [m74/m101].
// Key: bits(score) & ~31 | slot, kept with v_max_f32 (<=31 ulp perturbation,
// absorbed by exact top-2 rescore); slot = 2*stage+subtile recovers cidx.
__global__ __launch_bounds__(BLKT, 4) void vq_mfma_kernel(
    const float* __restrict__ enc, const float* __restrict__ cb,
    const u16* __restrict__ cb_hi, const float* __restrict__ hcsq,
    u64* __restrict__ winner)
{
    // loop phase: ldsb 2 bufs x 8KB (4096 u32) | lds_h 4KB (1024 u32) = 20 KB
    // epilogue:   keys[128][33] (4224 u32) reuses front; idxb at 4352 (lds_h
    // region, dead post-loop). Block LDS = 20480 B.
    __shared__ __align__(16) u32 smem[5120];
    u16*   ldsb  = (u16*)smem;                 // [0, 4096) u32
    float* lds_h = (float*)(smem + 4096);      // [4096, 5120) u32
    u32*   keys  = smem;                       // epilogue reuse [0, 4224)
    u32*   idxb  = smem + 4352;                // epilogue [4352, 4608)

    const int tid  = threadIdx.x;
    const int w    = tid >> 6;                             // 0..3
    const int lane = tid & 63;
    const int n32  = lane & 31;
    const int lh   = lane >> 5;
    const int B0   = blockIdx.y * SPLIT_K;
    const int rowbase = blockIdx.x * 128 + w * 32;         // 32 m-rows per wave

    // ---- A fragments: 1 m-tile x 4 k-chunks, converted once ----
    short8v a_hi[4];
    {
        const float* arow = enc + (size_t)(rowbase + n32) * D_DIM + lh * 8;
#pragma unroll
        for (int c = 0; c < 4; ++c) {
            const float4 u0 = ((const float4*)(arow + c * 16))[0];
            const float4 u1 = ((const float4*)(arow + c * 16))[1];
            const float vv[8] = {u0.x,u0.y,u0.z,u0.w,u1.x,u1.y,u1.z,u1.w};
            short8v h8;
#pragma unroll
            for (int j = 0; j < 8; ++j) h8[j] = (short)f2bf(vv[j]);
            a_hi[c] = h8;
        }
    }

    // ---- split's hcsq into LDS (once) ----
#pragma unroll
    for (int i = 0; i < SPLIT_K / BLKT; ++i)               // 4 iters
        lds_h[tid + i * BLKT] = hcsq[B0 + tid + i * BLKT];

    // ---- DMA: 8 granules/stage = 4 waves x 2; wave owns (u, c-parity) ----
    // granule slot = lane (n=lane&31, octet=2c+lh) -> contiguous b128 dest.
    const int uu = w & 1;                                  // 32-n subtile
    const int cp = w >> 1;                                 // c parity
    const u16* gbase = cb_hi + (size_t)B0 * D_DIM;

#define DMA_STAGE(buf_, s_)                                                      \
    do {                                                                         \
        _Pragma("unroll")                                                        \
        for (int i_ = 0; i_ < 2; ++i_) {                                         \
            const int c_ = cp + 2 * i_;                                          \
            __builtin_amdgcn_global_load_lds(                                    \
                (const __attribute__((address_space(1))) void*)                  \
                    (gbase + ((size_t)(s_) * STAGE + uu * 32 + n32) * D_DIM      \
                           + (2 * c_ + lh) * 8),                                 \
                (__attribute__((address_space(3))) void*)                        \
                    (ldsb + (buf_) * 4096 + uu * 2048 + c_ * 512),               \
                16, 0, 0);                                                       \
        }                                                                        \
    } while (0)

    DMA_STAGE(0, 0);
    __syncthreads();                                       // stage 0 resident

    f32x16 z;
#pragma unroll
    for (int r = 0; r < 16; ++r) z[r] = 0.f;               // never written: chain seed

    float bkey[16];
#pragma unroll
    for (int r = 0; r < 16; ++r) bkey[r] = -INFINITY;

    for (int s = 0; s < NSTAGES; ++s) {
        const int buf = s & 1;
        DMA_STAGE(buf ^ 1, (s + 1) & (NSTAGES - 1));       // async prefetch (wrap ok)

#pragma unroll
        for (int u = 0; u < 2; ++u) {                      // two 32-n subtiles
            const u16* bb = ldsb + buf * 4096 + u * 2048;
            short8v bh[4];
#pragma unroll
            for (int c = 0; c < 4; ++c)
                bh[c] = *(const short8v*)(bb + c * 512 + lane * 8);
            const float h = lds_h[s * STAGE + u * 32 + n32];
            const u32 slot = (u32)(s * 2 + u);             // 5 bits

            f32x16 acc;
            acc = __builtin_amdgcn_mfma_f32_32x32x16_bf16(a_hi[0], bh[0], z,   0,0,0);
            acc = __builtin_amdgcn_mfma_f32_32x32x16_bf16(a_hi[1], bh[1], acc, 0,0,0);
            acc = __builtin_amdgcn_mfma_f32_32x32x16_bf16(a_hi[2], bh[2], acc, 0,0,0);
            acc = __builtin_amdgcn_mfma_f32_32x32x16_bf16(a_hi[3], bh[3], acc, 0,0,0);

#pragma unroll
            for (int r = 0; r < 16; ++r) {
                const float sc = acc[r] - h;
                const u32 kb = (__float_as_uint(sc) & 0xFFFFFFE0u) | slot;
                bkey[r] = fmaxf(bkey[r], __uint_as_float(kb));
            }
        }
        __syncthreads();   // all waves done reading buf; prefetch drained (vmcnt0)
    }
#undef DMA_STAGE

    // ---- per-class winners -> keys[row][cls] in LDS (reuses ldsb region) ----
#pragma unroll
    for (int r = 0; r < 16; ++r) {
        const int m = (r & 3) + 8 * (r >> 2) + 4 * lh;
        keys[(w * 32 + m) * 33 + n32] = __float_as_uint(bkey[r]);
    }
    __syncthreads();

    // ---- top-2 of 32 classes (1 thread per row), handoff via LDS ----
    if (tid < 128) {
        float k1 = -INFINITY, k2 = -INFINITY; int c1i = 0, c2i = 0;
#pragma unroll
        for (int cls = 0; cls < 32; ++cls) {
            const float kf = __uint_as_float(keys[tid * 33 + cls]);
            if (kf > k1)      { k2 = k1; c2i = c1i; k1 = kf; c1i = cls; }
            else if (kf > k2) { k2 = kf; c2i = cls; }
        }
        idxb[tid * 2 + 0] = (u32)(B0 + (int)(__float_as_uint(k1) & 31u) * 32 + c1i);
        idxb[tid * 2 + 1] = (u32)(B0 + (int)(__float_as_uint(k2) & 31u) * 32 + c2i);
    }
    __syncthreads();

    // ---- exact fp32 rescore, 2 threads/row (one candidate each) ----
    {
        const int row  = tid >> 1;
        const int grow = blockIdx.x * 128 + row;
        const int idx  = (int)idxb[tid];

        const float4* xp = (const float4*)(enc + (size_t)grow * D_DIM);
        const float4* cp4 = (const float4*)(cb + (size_t)idx  * D_DIM);
        float d = 0.f;
#pragma unroll
        for (int i = 0; i < 16; ++i) {
            const float4 xv = xp[i], v = cp4[i];
            float t;
            t = xv.x - v.x; d = fmaf(t, t, d);
            t = xv.y - v.y; d = fmaf(t, t, d);
            t = xv.z - v.z; d = fmaf(t, t, d);
            t = xv.w - v.w; d = fmaf(t, t, d);
        }
        // (distbits, idx) packed: u64 min == (min dist, then min idx) = jnp first-min.
        // 0xAAAA... ws poison exceeds any packed value (dist sign bit 0): free sentinel.
        atomicMin(winner + grow, ((u64)__float_as_uint(d) << 32) | (u32)idx);
    }
}

// ---- kernel 2: gather winning codeword rows ----
__global__ void vq_gather_kernel(const float* __restrict__ cb,
                                 const u64* __restrict__ winner,
                                 float* __restrict__ out)
{
    const int g   = blockIdx.x * 256 + threadIdx.x;    // 262144 threads x 16B
    const int row = g >> 4;
    const int c4  = g & 15;
    const int idx = (int)(winner[row] & 0xFFFFFFFFu);
    ((float4*)(out + (size_t)row * D_DIM))[c4] =
        ((const float4*)(cb + (size_t)idx * D_DIM))[c4];
}

extern "C" void kernel_launch(void* const* d_in, const int* in_sizes, int n_in,
                              void* d_out, int out_size, void* d_ws, size_t ws_size,
                              hipStream_t stream) {
    const float* enc = (const float*)d_in[0];   // 16384 x 64 fp32
    const float* cb  = (const float*)d_in[1];   // 8192 x 64 fp32
    float* out = (float*)d_out;

    // ws layout (~1.16 MB): cb_hi | hcsq | winner
    u16* cb_hi  = (u16*)d_ws;                       // 1 MB
    float* hcsq = (float*)(cb_hi + K_CB * D_DIM);   // 32 KB
    u64* winner = (u64*)(hcsq + K_CB);              // 128 KB (8-byte aligned)

    vq_prep_kernel<<<K_CB / 8, 256, 0, stream>>>(cb, cb_hi, hcsq);

    dim3 g1(N_ROWS / 128, NSPLIT);                  // 128 x 8 = 1024 blocks of 256 thr
    vq_mfma_kernel<<<g1, BLKT, 0, stream>>>(enc, cb, cb_hi, hcsq, winner);

    vq_gather_kernel<<<(N_ROWS * 16) / 256, 256, 0, stream>>>(cb, winner, out);
}